// Round 1
// baseline (117.611 us; speedup 1.0000x reference)
//
#include <hip/hip_runtime.h>
#include <stdint.h>

// LocallyConnected1d: out[b,c,o] = (1/8) * sum_{i<64,k<8} x[b,i,4o+k] * w[c,i,o,k]
// B=128, CIN=64, COUT=64, OUT_DIM=256, K=8, S=4, L=1028. fp32 in/out.
//
// R4: two-phase. K1 transposes+converts w into bf16 workspace laid out EXACTLY
// as K2's LDS B-tile (bank-XOR baked in), so K2's w staging is a flat
// global_load_lds dwordx4 copy (zero VALU). K2: block = (o-pair q, b-quarter),
// grid 512 (2 blocks/CU), x read direct fp32 (windows shared by the o-pair),
// mfma_f32_16x16x32_bf16. XCD swizzle: q-ranges pinned per XCD so the 2.1 MB
// wb slab L2-caches and out-lines (16 consecutive o) merge in one L2.

#define B_    128
#define CIN_  64
#define COUT_ 64
#define OD_   256
#define K_    8
#define L_    1028

// wb layout: [q 128][ch 4][o_lo 2][c 64][gs 16][k 8] bf16, gs = i_loc ^ (c&7)
#define WB_PER_Q  65536
#define WB_PER_CH 16384

#define ASTR 20   // A_lds row stride in bf16 elems (40 B: non-pow2 -> <=2-way banks)

typedef __attribute__((ext_vector_type(8))) short bf16x8;
typedef __attribute__((ext_vector_type(4))) short short4v;
typedef __attribute__((ext_vector_type(4))) float floatx4;

__device__ __forceinline__ unsigned short f32_to_bf16(float f) {
    union { float f; uint32_t u; } v; v.f = f;
    uint32_t u = v.u;
    u += 0x7FFFu + ((u >> 16) & 1u);   // round-to-nearest-even
    return (unsigned short)(u >> 16);
}

// ---------------- K1: w fp32 -> wb bf16 (transpose + swizzle) ----------------
// grid 512 = 8 c-tiles(8) x 4 i-tiles(16) x 16 o-tiles(16). 256 threads.
__global__ __launch_bounds__(256, 2)
void lc1d_wprep(const float* __restrict__ w, unsigned short* __restrict__ wb) {
    __shared__ __align__(16) unsigned short tile[128 * 136];  // (c,i) rows x (16o x 8k), pad 8

    const int tid = threadIdx.x;
    const int bx  = blockIdx.x;
    const int c0  = (bx & 7) * 8;
    const int ch  = (bx >> 3) & 3;
    const int i0  = ch * 16;
    const int ot  = bx >> 5;           // 0..15
    const int o0  = ot * 16;
    const int q0  = ot * 8;

    // read: 128 rows (c,i) x 512 B contiguous (16 o x 8 k floats)
    #pragma unroll
    for (int it = 0; it < 16; ++it) {
        const int u   = it * 256 + tid;
        const int t   = u & 31;         // float4 within row
        const int row = u >> 5;         // cL*16 + iL
        const int iL  = row & 15;
        const int cL  = row >> 4;
        const float4 v = *(const float4*)(w +
            (size_t)((c0 + cL) * CIN_ + (i0 + iL)) * (OD_ * K_) + o0 * K_ + t * 4);
        ushort4 sv = make_ushort4(f32_to_bf16(v.x), f32_to_bf16(v.y),
                                  f32_to_bf16(v.z), f32_to_bf16(v.w));
        *(ushort4*)&tile[row * 136 + t * 4] = sv;
    }
    __syncthreads();

    // write: granule (qL, o_lo, cL, gs) -> contiguous 16 B stores in wb order
    #pragma unroll
    for (int it = 0; it < 8; ++it) {
        const int u    = it * 256 + tid;
        const int gs   = u & 15;
        const int cL   = (u >> 4) & 7;
        const int o_lo = (u >> 7) & 1;
        const int qL   = u >> 8;        // 0..7
        const int c    = c0 + cL;
        const int iL   = gs ^ (c & 7);  // bank-XOR baked into stored position
        const int row  = cL * 16 + iL;
        const int o_loc = qL * 2 + o_lo;
        const bf16x8 vv = *(const bf16x8*)&tile[row * 136 + o_loc * 8];
        const size_t dst = (size_t)(q0 + qL) * WB_PER_Q + (size_t)ch * WB_PER_CH
                         + ((size_t)((o_lo * 64 + c) * 16 + gs) << 3);
        *(bf16x8*)&wb[dst] = vv;
    }
}

// ---------------- K2: GEMM. block = (q, b-quarter), grid 512 ----------------
__global__ __launch_bounds__(256, 2)
void lc1d_gemm(const float* __restrict__ x,
               const unsigned short* __restrict__ wb,
               float* __restrict__ out) {
    __shared__ __align__(16) unsigned short Bl[16384];           // 32 KB, flat = wb chunk
    __shared__ __align__(16) unsigned short Al[16 * 32 * ASTR];  // 20 KB

    const int tid = threadIdx.x;
    const int blk = blockIdx.x;
    // XCD swizzle: XCD k hosts q in [16k,16k+16) for all b-quarters
    const int q   = (blk & 7) * 16 + ((blk >> 3) & 15);
    const int bq  = blk >> 7;           // 0..3
    const int b0  = bq * 32;

    const int wave = tid >> 6;
    const int lane = tid & 63;
    const int quad = lane >> 4;
    const int l16  = lane & 15;
    const int o_lo = wave & 1;          // which o of the pair
    const int ms   = wave >> 1;         // m-stripe (16 b rows)

    floatx4 acc[4];
    #pragma unroll
    for (int nt = 0; nt < 4; ++nt) acc[nt] = (floatx4){0.f, 0.f, 0.f, 0.f};

    for (int ch = 0; ch < 4; ++ch) {
        // ---- w staging: flat async copy wb[q][ch] -> Bl (32 KB), zero VALU ----
        const char* wsrc = (const char*)(wb + (size_t)q * WB_PER_Q + (size_t)ch * WB_PER_CH);
        #pragma unroll
        for (int j = 0; j < 8; ++j) {
            const int off = wave * 8192 + j * 1024;
            auto gp = (const __attribute__((address_space(1))) uint32_t*)(wsrc + off + lane * 16);
            auto lp = (__attribute__((address_space(3))) uint32_t*)((char*)&Bl[0] + off);
            __builtin_amdgcn_global_load_lds(gp, lp, 16, 0, 0);
        }

        // ---- x staging: rows (b,i) x 12 floats [8q, 8q+12) covering both o's ----
        #pragma unroll
        for (int it = 0; it < 8; ++it) {
            const int u   = it * 256 + tid;
            const int t   = u & 3;          // float4 within row; t==3 unused/masked
            const int row = u >> 2;         // 0..511
            const int iL  = row & 15;
            const int b   = row >> 4;       // 0..31
            if (t < 3) {
                const float4 v = *(const float4*)(x +
                    (size_t)((b0 + b) * CIN_ + ch * 16 + iL) * L_ + q * 8 + t * 4);
                ushort4 sv = make_ushort4(f32_to_bf16(v.x), f32_to_bf16(v.y),
                                          f32_to_bf16(v.z), f32_to_bf16(v.w));
                *(ushort4*)&Al[(iL * 32 + b) * ASTR + t * 4] = sv;
            }
        }
        __syncthreads();   // drains vmcnt (DMA) + lgkm (LDS stores)

        // ---- compute: 4 k-steps of 32 (i_loc = kt*4+quad, k=quad*8+j) ----
        #pragma unroll
        for (int kt = 0; kt < 4; ++kt) {
            const int i_l   = kt * 4 + quad;
            const int abase = (i_l * 32 + ms * 16 + l16) * ASTR + o_lo * 4;
            const short4v a_lo = *(const short4v*)&Al[abase];
            const short4v a_hi = *(const short4v*)&Al[abase + 4];
            bf16x8 af;
            af[0] = a_lo[0]; af[1] = a_lo[1]; af[2] = a_lo[2]; af[3] = a_lo[3];
            af[4] = a_hi[0]; af[5] = a_hi[1]; af[6] = a_hi[2]; af[7] = a_hi[3];
            #pragma unroll
            for (int nt = 0; nt < 4; ++nt) {
                const int c  = nt * 16 + l16;
                const int gs = i_l ^ (c & 7);
                const bf16x8 bf = *(const bf16x8*)&Bl[((o_lo * 64 + c) * 16 + gs) << 3];
                acc[nt] = __builtin_amdgcn_mfma_f32_16x16x32_bf16(af, bf, acc[nt], 0, 0, 0);
            }
        }
        __syncthreads();   // LDS reads done before next chunk overwrites
    }

    // ---- epilogue: D col=lane&15 (c), row=quad*4+reg (b); scale 1/sqrt(64) ----
    const int o_g = q * 2 + o_lo;
    #pragma unroll
    for (int nt = 0; nt < 4; ++nt) {
        const int c = nt * 16 + l16;
        #pragma unroll
        for (int r = 0; r < 4; ++r) {
            const int b = b0 + ms * 16 + quad * 4 + r;
            out[((size_t)b * COUT_ + c) * OD_ + o_g] = acc[nt][r] * 0.125f;
        }
    }
}

extern "C" void kernel_launch(void* const* d_in, const int* in_sizes, int n_in,
                              void* d_out, int out_size, void* d_ws, size_t ws_size,
                              hipStream_t stream) {
    const float* x = (const float*)d_in[0];   // (128, 64, 1028)
    const float* w = (const float*)d_in[1];   // (1, 64, 64, 256, 8)
    float* out = (float*)d_out;               // (128, 64, 256)
    unsigned short* wb = (unsigned short*)d_ws; // 16.8 MB bf16 workspace

    hipLaunchKernelGGL(lc1d_wprep, dim3(512), dim3(256), 0, stream, w, wb);
    hipLaunchKernelGGL(lc1d_gemm,  dim3(512), dim3(256), 0, stream, x, wb, out);
}